// Round 1
// baseline (155.807 us; speedup 1.0000x reference)
//
#include <hip/hip_runtime.h>

#define B_    4
#define N_    20000
#define M_    20000
#define K_    16
#define CIN   64
#define CMID  16
#define CADD  3
#define COUT  67          // CIN + CADD
#define PPB   16          // points per block (4 per wave, 16 lanes per point)

typedef float float4_ __attribute__((ext_vector_type(4)));

__global__ __launch_bounds__(256, 2) void pconv_kernel(
    const float* __restrict__ in_feats,   // [B, N, 64]
    const int*   __restrict__ inds,       // [B, M, 16]
    const float* __restrict__ wn,         // [B, M, 16, 16]
    const float* __restrict__ addl,       // [B, M, 16, 3]
    float*       __restrict__ out)        // [B, M, 1072]
{
    const int tid  = threadIdx.x;
    const int lane = tid & 63;
    const int wav  = tid >> 6;                 // wave in block, 0..3
    const int pl   = lane & 15;                // lane within point
    const int pib  = wav * 4 + (lane >> 4);    // point within block, 0..15
    const int cg   = pl >> 2;                  // c-block (16 channels each), 0..3
    const int wg   = pl & 3;                   // w-block (4 outputs each), 0..3

    const long bp  = (long)blockIdx.x * PPB + pib;   // global point index, 0..B*M-1
    const int  b   = (int)(bp / M_);                 // batch (for input_features)

    const int*   pinds = inds + bp * K_;
    const float* pwn   = wn   + bp * (K_ * CMID);
    const float* padd  = addl + bp * (K_ * CADD);
    const float* bfeat = in_feats + (long)b * N_ * CIN;

    float4_ acc[16];                 // 16 c-rows x 4 w-cols (float4 over w)
    #pragma unroll
    for (int i = 0; i < 16; ++i) acc[i] = (float4_)0.f;
    float4_ acc2 = (float4_)0.f;     // extra channel c = 64 + cg (cg < 3)

    #pragma unroll 4
    for (int k = 0; k < K_; ++k) {
        const int idx = pinds[k];
        const float* row = bfeat + (long)idx * CIN + cg * 16;
        float4_ wv = *(const float4_*)(pwn + k * CMID + wg * 4);
        float   av = (cg < 3) ? padd[k * CADD + cg] : 0.f;
        #pragma unroll
        for (int i4 = 0; i4 < 4; ++i4) {
            float4_ fv = *(const float4_*)(row + i4 * 4);
            #pragma unroll
            for (int e = 0; e < 4; ++e) {
                acc[i4 * 4 + e] += fv[e] * wv;
            }
        }
        acc2 += av * wv;
    }

    // main store: c = cg*16 + i, w = wg*4 + j  -> float4 per i
    float* pout = out + bp * (COUT * CMID) + cg * (16 * CMID) + wg * 4;
    #pragma unroll
    for (int i = 0; i < 16; ++i) {
        *(float4_*)(pout + i * CMID) = acc[i];
    }
    // epilogue store: additional-feature channels c = 64..66
    if (cg < 3) {
        float* pout2 = out + bp * (COUT * CMID) + (CIN + cg) * CMID + wg * 4;
        *(float4_*)pout2 = acc2;
    }
}

extern "C" void kernel_launch(void* const* d_in, const int* in_sizes, int n_in,
                              void* d_out, int out_size, void* d_ws, size_t ws_size,
                              hipStream_t stream) {
    const float* in_feats = (const float*)d_in[0];
    const int*   ninds    = (const int*)d_in[1];
    const float* wn       = (const float*)d_in[2];
    const float* addl     = (const float*)d_in[3];
    float*       out      = (float*)d_out;

    const int total_points = B_ * M_;            // 80000
    dim3 grid(total_points / PPB);               // 5000 blocks
    dim3 block(256);
    pconv_kernel<<<grid, block, 0, stream>>>(in_feats, ninds, wn, addl, out);
}